// Round 9
// baseline (97.405 us; speedup 1.0000x reference)
//
#include <hip/hip_runtime.h>
#include <hip/hip_bf16.h>

// DirectionalConv mode='down': out[b,co,d,h,w] =
//   sum_{ci,i,k} x[b,ci, d+i-2, h+i-2, w+k-2] * W[co,ci,i,0,k] + bias[co]
// x: (2,32,48,64,128) f32, W: (32,32,5,1,5), out: (2,32,48,68,128) f32.
//
// R9: persistent 2-quad blocks along a diagonal. Quad A = (d0+q, h0+q),
// quad B = (d0+4+q, h1+q); they share 4 of 8 staged planes (ring slots,
// slot = plane index mod 8). New planes prefetched into regs during quad-A
// MFMA (T14), written after a barrier. Swizzle s = col&7 (R8, conflict-floor).

#define NB   2
#define CIN  32
#define COUT 32
#define DD   48
#define HH   64
#define WW   128
#define DOUT 48
#define HO   68
#define WO   128

#define RS   256            // ushorts per col = 32 16B-chunks (8 slots * 4 octs)
#define NCOL 132            // col = w + 2; cols 0,1,130,131 always zero

typedef __attribute__((ext_vector_type(8))) short bf16x8;
typedef __attribute__((ext_vector_type(4))) float f32x4;

__device__ __forceinline__ unsigned short f32_to_bf16(float v) {
    unsigned int u; __builtin_memcpy(&u, &v, 4);
    u += 0x7FFFu + ((u >> 16) & 1u);        // RNE
    return (unsigned short)(u >> 16);
}
// packed pair conversion -> v_cvt_pk_bf16_f32 (1 instr for 2 floats)
__device__ __forceinline__ unsigned int pk2(float a, float b) {
    float2 t; t.x = a; t.y = b;
    __hip_bfloat162 r = __float22bfloat162_rn(t);
    unsigned int u; __builtin_memcpy(&u, &r, 4);
    return u;
}

// Pre-pack weights into MFMA A-fragment order, kk-major:
// frag f = (kk*5 + c)*2 + mt ; lane l ; 8 bf16 = W[mt*16+(l&15)][ci=(l>>4)*8+j][i=c][kk]
__global__ void prep_weights_kernel(const float* __restrict__ wgt,
                                    unsigned int* __restrict__ ws) {
    int s = blockIdx.x * 256 + threadIdx.x;     // 50 frags * 64 lanes = 3200 slots
    if (s >= 3200) return;
    int f = s >> 6, l = s & 63;
    int mt = f & 1, kkc = f >> 1;
    int kk = kkc / 5, c = kkc - kk * 5;         // kk-major
    int co = mt * 16 + (l & 15);
    int cib = (l >> 4) * 8;
    unsigned int u[4];
#pragma unroll
    for (int jp = 0; jp < 4; ++jp) {
        float v0 = wgt[co * 800 + (cib + 2 * jp + 0) * 25 + c * 5 + kk];
        float v1 = wgt[co * 800 + (cib + 2 * jp + 1) * 25 + c * 5 + kk];
        u[jp] = (unsigned int)f32_to_bf16(v0) | ((unsigned int)f32_to_bf16(v1) << 16);
    }
    uint4 pack; pack.x = u[0]; pack.y = u[1]; pack.z = u[2]; pack.w = u[3];
    reinterpret_cast<uint4*>(ws)[s] = pack;
}

__global__ void __launch_bounds__(512, 4)
dconv_kernel(const float* __restrict__ x,
             const float* __restrict__ bias,
             const bf16x8* __restrict__ wsf,   // packed A fragments
             float* __restrict__ out) {
    __shared__ __align__(16) unsigned short xs[NCOL * RS];   // 67584 B

    const int tid  = threadIdx.x;
    const int lane = tid & 63;
    const int wv   = tid >> 6;          // 0..7
    const int lr   = lane & 15;
    const int lg   = lane >> 4;
    const int mt   = wv & 1;            // co-half owned by this wave (MFMA phase)
    const int wbase = (wv >> 1) * 32;   // 32-wide w-tile (MFMA phase)

    // ---- bijective 8-XCD chunked remap (852 = 8*106 + 4, m204 formula) ----
    {
    }
    int bid = blockIdx.x;
    int xcd = bid & 7, idx = bid >> 3;
    int e   = (xcd < 4) ? (xcd * 107 + idx) : (4 * 107 + (xcd - 4) * 106 + idx);
    int b   = (e >= 426) ? 1 : 0;
    int r0  = e - b * 426;
    int dlt = r0 / 6;                   // 0..70
    int ssb = r0 - dlt * 6;             // 0..5
    const int d0 = 8 * ssb;             // quad A depth base
    const int h0 = (d0 + dlt) % 71 - 3; // -3..67
    const int d1 = d0 + 4;              // quad B depth base
    const int h1 = (d1 + dlt) % 71 - 3;
    const bool wrapped = (h1 != h0 + 4);    // diagonal wrapped mid-block (~6%)

    // ---- early issue: quad-A kk=0 A-fragments + bias ----
    const bf16x8* wl = wsf + lane;          // frag f at wl[f*64]
    bf16x8 aA[5], aB[5];
#pragma unroll
    for (int c = 0; c < 5; ++c) aA[c] = wl[(c * 2 + mt) * 64];
    float bs[4];
#pragma unroll
    for (int rg = 0; rg < 4; ++rg) bs[rg] = bias[mt * 16 + lg * 4 + rg];

    // ---- zero the 4 always-zero halo cols (0,1,130,131), all 32 chunks ----
    if (tid < 128) {
        int colIdx = tid >> 5;              // 0..3
        int ch     = tid & 31;              // 0..31
        int col    = (colIdx < 2) ? colIdx : 128 + colIdx;
        f32x4 z = {};
        *reinterpret_cast<f32x4*>(&xs[col * RS + ch * 8]) = z;
    }

    // ---- staging geometry: col-per-lane (R8) ----
    const int oct = wv >> 1, wh = wv & 1;
    const int w0s = wh * 64 + lane;         // 0..127
    const int cols = w0s + 2;
    const int ssw  = cols & 7;              // swizzle key
    unsigned short* cbase = &xs[cols * RS];
    const size_t plane = (size_t)DD * HH * WW;
    const float* xoct = x + ((size_t)b * CIN + oct * 8) * plane + w0s;

    // stage one plane into ring slot: load 8 ci, pack bf16, one b128 write
#define STAGE1(SLOT, DZ, HZ)                                                   \
    {                                                                          \
        int dz = (DZ), hz = (HZ);                                              \
        float v[8];                                                            \
        _Pragma("unroll") for (int k = 0; k < 8; ++k) v[k] = 0.f;              \
        if (((unsigned)dz < (unsigned)DD) && ((unsigned)hz < (unsigned)HH)) {  \
            const float* p = xoct + ((size_t)dz * HH + hz) * WW;               \
            _Pragma("unroll") for (int k = 0; k < 8; ++k)                      \
                v[k] = p[(size_t)k * plane];                                   \
        }                                                                      \
        uint4 ch;                                                              \
        ch.x = pk2(v[0], v[1]); ch.y = pk2(v[2], v[3]);                        \
        ch.z = pk2(v[4], v[5]); ch.w = pk2(v[6], v[7]);                        \
        *reinterpret_cast<uint4*>(cbase + ((((SLOT) * 4 + oct) ^ ssw) * 8)) = ch; \
    }

    // ---- phase A: stage planes d0-2 .. d0+5 into slots 0..7 ----
#pragma unroll
    for (int j = 0; j < 8; ++j) STAGE1(j, d0 - 2 + j, h0 - 2 + j);
    __syncthreads();

    f32x4 acc[4][2] = {};   // [q][nt]

#define PREFA(DST, KK1)                                                        \
    _Pragma("unroll") for (int c = 0; c < 5; ++c)                              \
        DST[c] = wl[(((KK1) * 5 + c) * 2 + mt) * 64];

    // one kk step; SOFF = ring-slot offset (0 for quad A, 4 for quad B).
    // phys chunk P = (slot ^ sb)*4 + (lg ^ (s&3)); even/odd-slot two-pointer.
#define STEPK(KK, ACU, SOFF)                                                   \
    {                                                                          \
        __builtin_amdgcn_s_setprio(1);                                         \
        _Pragma("unroll") for (int nt = 0; nt < 2; ++nt) {                     \
            const int col = wbase + nt * 16 + lr + (KK);                       \
            const int s   = col & 7;                                           \
            const int sb  = s >> 2;                                            \
            const int lg2 = lg ^ (s & 3);                                      \
            const unsigned short* pc = &xs[col * RS + lg2 * 8];                \
            const unsigned short* pE = pc + sb * 32;                           \
            const unsigned short* pO = pc - sb * 32;                           \
            _Pragma("unroll") for (int j = 0; j < 8; ++j) {                    \
                const int slot = (j + (SOFF)) & 7;                             \
                const unsigned short* p = (slot & 1) ? pO : pE;                \
                bf16x8 bv = *reinterpret_cast<const bf16x8*>(p + slot * 32);   \
                const int qlo = (j > 4) ? (j - 4) : 0;                         \
                const int qhi = (j < 3) ? j : 3;                               \
                _Pragma("unroll") for (int q = qlo; q <= qhi; ++q) {           \
                    acc[q][nt] = __builtin_amdgcn_mfma_f32_16x16x32_bf16(      \
                        ACU[j - q], bv, acc[q][nt], 0, 0, 0);                  \
                }                                                              \
            }                                                                  \
        }                                                                      \
        __builtin_amdgcn_s_setprio(0);                                         \
    }

#define EPI(DQ, HQ)                                                            \
    _Pragma("unroll") for (int q = 0; q < 4; ++q) {                            \
        const int hq = (HQ) + q;                                               \
        if (hq >= 0 && hq < HO) {                                              \
            const int dq = (DQ) + q;                                           \
            _Pragma("unroll") for (int nt = 0; nt < 2; ++nt) {                 \
                const int w = wbase + nt * 16 + lr;                            \
                _Pragma("unroll") for (int rg = 0; rg < 4; ++rg) {             \
                    int co = mt * 16 + lg * 4 + rg;                            \
                    out[((((size_t)b * COUT + co) * DOUT + dq) * HO + hq) * WO + w] \
                        = acc[q][nt][rg] + bs[rg];                             \
                }                                                              \
            }                                                                  \
        }                                                                      \
    }

    // ---- quad A: kk ping-pong; prefetch quad-B's 4 new planes late ----
    PREFA(aB, 1) STEPK(0, aA, 0)
    PREFA(aA, 2) STEPK(1, aB, 0)
    PREFA(aB, 3) STEPK(2, aA, 0)
    PREFA(aA, 4) STEPK(3, aB, 0)

    float pre[4][8];                        // T14: issue-early, write-late
    if (!wrapped) {
#pragma unroll
        for (int jj = 0; jj < 4; ++jj) {
            int dz = d0 + 6 + jj, hz = h0 + 6 + jj;
#pragma unroll
            for (int k = 0; k < 8; ++k) pre[jj][k] = 0.f;
            if (((unsigned)dz < (unsigned)DD) && ((unsigned)hz < (unsigned)HH)) {
                const float* p = xoct + ((size_t)dz * HH + hz) * WW;
#pragma unroll
                for (int k = 0; k < 8; ++k) pre[jj][k] = p[(size_t)k * plane];
            }
        }
    }

    STEPK(4, aA, 0)
    PREFA(aB, 0)                            // quad-B kk=0 frags (cover barrier)
    EPI(d0, h0)
    __syncthreads();

    // ---- phase B: write quad-B's new planes into freed slots ----
    if (!wrapped) {
        // planes d1+2..d1+5 -> slots 0..3 (ring), from prefetched regs
#pragma unroll
        for (int jj = 0; jj < 4; ++jj) {
            uint4 ch;
            ch.x = pk2(pre[jj][0], pre[jj][1]); ch.y = pk2(pre[jj][2], pre[jj][3]);
            ch.z = pk2(pre[jj][4], pre[jj][5]); ch.w = pk2(pre[jj][6], pre[jj][7]);
            *reinterpret_cast<uint4*>(cbase + (((jj * 4 + oct) ^ ssw) * 8)) = ch;
        }
    } else {
        // diagonal wrapped: quad B unrelated to quad A; restage all 8 planes
#pragma unroll
        for (int j1 = 0; j1 < 8; ++j1)
            STAGE1((j1 + 4) & 7, d1 - 2 + j1, h1 - 2 + j1);
    }
    __syncthreads();

    // ---- quad B: slots offset by 4 ----
#pragma unroll
    for (int q = 0; q < 4; ++q)
#pragma unroll
        for (int nt = 0; nt < 2; ++nt) acc[q][nt] = (f32x4){0.f, 0.f, 0.f, 0.f};

    PREFA(aA, 1) STEPK(0, aB, 4)
    PREFA(aB, 2) STEPK(1, aA, 4)
    PREFA(aA, 3) STEPK(2, aB, 4)
    PREFA(aB, 4) STEPK(3, aA, 4)
    STEPK(4, aB, 4)
    EPI(d1, h1)

#undef PREFA
#undef STEPK
#undef EPI
#undef STAGE1
}

extern "C" void kernel_launch(void* const* d_in, const int* in_sizes, int n_in,
                              void* d_out, int out_size, void* d_ws, size_t ws_size,
                              hipStream_t stream) {
    const float* x    = (const float*)d_in[0];
    const float* wgt  = (const float*)d_in[1];
    const float* bias = (const float*)d_in[2];
    float* out = (float*)d_out;
    unsigned int* ws = (unsigned int*)d_ws;

    // pack weights into A-fragment layout (51200 B in d_ws)
    prep_weights_kernel<<<13, 256, 0, stream>>>(wgt, ws);

    dconv_kernel<<<852, 512, 0, stream>>>(x, bias, (const bf16x8*)ws, out);
}

// Round 10
// 79.788 us; speedup vs baseline: 1.2208x; 1.2208x over previous
//
#include <hip/hip_runtime.h>
#include <hip/hip_bf16.h>

// DirectionalConv mode='down': out[b,co,d,h,w] =
//   sum_{ci,i,k} x[b,ci, d+i-2, h+i-2, w+k-2] * W[co,ci,i,0,k] + bias[co]
// x: (2,32,48,64,128) f32, W: (32,32,5,1,5), out: (2,32,48,68,128) f32.
//
// R10: quad-diagonal x 64-wide-w blocks (256 thr, 34.8 KB LDS -> 4 blocks/CU)
// for 4 independent staging streams per CU (R8 was latency-bound at 2).
// Swizzle s = col&7 on 16B chunks (R8, conflict-floor on read AND write).

#define NB   2
#define CIN  32
#define COUT 32
#define DD   48
#define HH   64
#define WW   128
#define DOUT 48
#define HO   68
#define WO   128

#define RS    256           // ushorts per col = 32 16B-chunks (8 planes * 4 octs)
#define NCOL  68            // local col = w - wlo + 2; 64 w + 4 halo

typedef __attribute__((ext_vector_type(8))) short bf16x8;
typedef __attribute__((ext_vector_type(4))) float f32x4;

__device__ __forceinline__ unsigned short f32_to_bf16(float v) {
    unsigned int u; __builtin_memcpy(&u, &v, 4);
    u += 0x7FFFu + ((u >> 16) & 1u);        // RNE
    return (unsigned short)(u >> 16);
}
// packed pair conversion -> v_cvt_pk_bf16_f32 (1 instr for 2 floats)
__device__ __forceinline__ unsigned int pk2(float a, float b) {
    float2 t; t.x = a; t.y = b;
    __hip_bfloat162 r = __float22bfloat162_rn(t);
    unsigned int u; __builtin_memcpy(&u, &r, 4);
    return u;
}

// Pre-pack weights into MFMA A-fragment order, kk-major:
// frag f = (kk*5 + c)*2 + mt ; lane l ; 8 bf16 = W[mt*16+(l&15)][ci=(l>>4)*8+j][i=c][kk]
__global__ void prep_weights_kernel(const float* __restrict__ wgt,
                                    unsigned int* __restrict__ ws) {
    int s = blockIdx.x * 256 + threadIdx.x;     // 50 frags * 64 lanes = 3200 slots
    if (s >= 3200) return;
    int f = s >> 6, l = s & 63;
    int mt = f & 1, kkc = f >> 1;
    int kk = kkc / 5, c = kkc - kk * 5;         // kk-major
    int co = mt * 16 + (l & 15);
    int cib = (l >> 4) * 8;
    unsigned int u[4];
#pragma unroll
    for (int jp = 0; jp < 4; ++jp) {
        float v0 = wgt[co * 800 + (cib + 2 * jp + 0) * 25 + c * 5 + kk];
        float v1 = wgt[co * 800 + (cib + 2 * jp + 1) * 25 + c * 5 + kk];
        u[jp] = (unsigned int)f32_to_bf16(v0) | ((unsigned int)f32_to_bf16(v1) << 16);
    }
    uint4 pack; pack.x = u[0]; pack.y = u[1]; pack.z = u[2]; pack.w = u[3];
    reinterpret_cast<uint4*>(ws)[s] = pack;
}

__global__ void __launch_bounds__(256, 4)
dconv_kernel(const float* __restrict__ x,
             const float* __restrict__ bias,
             const bf16x8* __restrict__ wsf,   // packed A fragments
             float* __restrict__ out) {
    __shared__ __align__(16) unsigned short xs[NCOL * RS];   // 34816 B

    const int tid  = threadIdx.x;
    const int lane = tid & 63;
    const int wv   = tid >> 6;          // 0..3
    const int lr   = lane & 15;
    const int lg   = lane >> 4;
    const int mt   = wv & 1;            // co-half owned by this wave (MFMA phase)
    const int wbl  = (wv >> 1) * 32;    // local 32-wide w-tile base (MFMA phase)

    // ---- XCD-chunked remap: 3408 = 8 * 426; w-half outermost per chunk,
    //      diagonal walk inner (consecutive e share 4/8 planes in L2) ----
    int bid = blockIdx.x;
    int e   = (bid & 7) * 426 + (bid >> 3);
    int wh  = (e >= 1704) ? 1 : 0;
    int qi  = e - wh * 1704;
    int b   = (qi >= 852) ? 1 : 0;
    int r0  = qi - b * 852;
    int dlt = r0 / 12;                  // 0..70
    int qq  = r0 - dlt * 12;            // 0..11
    const int d0  = 4 * qq;
    const int h0  = (d0 + dlt) % 71 - 3;    // -3..67
    const int wlo = wh * 64;

    // ---- early issue: kk=0 A-fragments + bias (hide under staging) ----
    const bf16x8* wl = wsf + lane;          // frag f at wl[f*64]
    bf16x8 aA[5], aB[5];
#pragma unroll
    for (int c = 0; c < 5; ++c) aA[c] = wl[(c * 2 + mt) * 64];
    float bs[4];
#pragma unroll
    for (int rg = 0; rg < 4; ++rg) bs[rg] = bias[mt * 16 + lg * 4 + rg];

    // ---- stage 8 diagonal planes: col-per-lane, wave = ci-oct ----
    // local col = global w - wlo + 2; halo/OOB cols zero via bounds checks.
    {
        const int oct = wv;                 // 0..3
        const size_t plane = (size_t)DD * HH * WW;
#pragma unroll
        for (int cc = 0; cc < 2; ++cc) {
            const int col = lane + 64 * cc;         // 0..63, then 64..67
            if (cc == 1 && lane >= 4) break;
            const int wg  = wlo + col - 2;          // global w
            const bool wok = (unsigned)wg < (unsigned)WW;
            const int s = col & 7;
            unsigned short* cbase = &xs[col * RS];
            const float* xoct = x + ((size_t)b * CIN + oct * 8) * plane + wg;
#pragma unroll 4
            for (int j = 0; j < 8; ++j) {
                int dz = d0 + j - 2, hz = h0 + j - 2;
                float v[8];
#pragma unroll
                for (int k = 0; k < 8; ++k) v[k] = 0.f;
                if (wok && ((unsigned)dz < (unsigned)DD) &&
                    ((unsigned)hz < (unsigned)HH)) {
                    const float* p = xoct + ((size_t)dz * HH + hz) * WW;
#pragma unroll
                    for (int k = 0; k < 8; ++k) v[k] = p[(size_t)k * plane];
                }
                uint4 ch;
                ch.x = pk2(v[0], v[1]); ch.y = pk2(v[2], v[3]);
                ch.z = pk2(v[4], v[5]); ch.w = pk2(v[6], v[7]);
                *reinterpret_cast<uint4*>(cbase + (((j * 4 + oct) ^ s) * 8)) = ch;
            }
        }
    }
    __syncthreads();

    // ---- MFMA: wave = (mt, 32 local w, 4 q); full-kk ping-pong A prefetch ----
    f32x4 acc[4][2] = {};   // [q][nt]

#define PREFA(DST, KK1)                                                        \
    _Pragma("unroll") for (int c = 0; c < 5; ++c)                              \
        DST[c] = wl[(((KK1) * 5 + c) * 2 + mt) * 64];

    // phys chunk for (j, lg) at col: P = (j ^ sb)*4 + (lg ^ (s&3)), sb = s>>2.
    // two-pointer form: even j -> pE + j*32, odd j -> pO + j*32 (ushorts).
#define STEPK(KK, ACU)                                                         \
    {                                                                          \
        __builtin_amdgcn_s_setprio(1);                                         \
        _Pragma("unroll") for (int nt = 0; nt < 2; ++nt) {                     \
            const int col = wbl + nt * 16 + lr + (KK);      /* 0..67 */        \
            const int s   = col & 7;                                           \
            const int sb  = s >> 2;                                            \
            const int lg2 = lg ^ (s & 3);                                      \
            const unsigned short* pc = &xs[col * RS + lg2 * 8];                \
            const unsigned short* pE = pc + sb * 32;                           \
            const unsigned short* pO = pc - sb * 32;                           \
            _Pragma("unroll") for (int j = 0; j < 8; ++j) {                    \
                const unsigned short* p = (j & 1) ? pO : pE;                   \
                bf16x8 bv = *reinterpret_cast<const bf16x8*>(p + j * 32);      \
                const int qlo = (j > 4) ? (j - 4) : 0;                         \
                const int qhi = (j < 3) ? j : 3;                               \
                _Pragma("unroll") for (int q = qlo; q <= qhi; ++q) {           \
                    acc[q][nt] = __builtin_amdgcn_mfma_f32_16x16x32_bf16(      \
                        ACU[j - q], bv, acc[q][nt], 0, 0, 0);                  \
                }                                                              \
            }                                                                  \
        }                                                                      \
        __builtin_amdgcn_s_setprio(0);                                         \
    }

    PREFA(aB, 1) STEPK(0, aA)
    PREFA(aA, 2) STEPK(1, aB)
    PREFA(aB, 3) STEPK(2, aA)
    PREFA(aA, 4) STEPK(3, aB)
    STEPK(4, aA)
#undef PREFA
#undef STEPK

    // ---- epilogue: D col=lane&15 (w), row=(lane>>4)*4+reg (co) ----
#pragma unroll
    for (int q = 0; q < 4; ++q) {
        const int hq = h0 + q;
        if (hq < 0 || hq >= HO) continue;
        const int dq = d0 + q;
#pragma unroll
        for (int nt = 0; nt < 2; ++nt) {
            const int w = wlo + wbl + nt * 16 + lr;
#pragma unroll
            for (int rg = 0; rg < 4; ++rg) {
                int co = mt * 16 + lg * 4 + rg;
                out[((((size_t)b * COUT + co) * DOUT + dq) * HO + hq) * WO + w] =
                    acc[q][nt][rg] + bs[rg];
            }
        }
    }
}

extern "C" void kernel_launch(void* const* d_in, const int* in_sizes, int n_in,
                              void* d_out, int out_size, void* d_ws, size_t ws_size,
                              hipStream_t stream) {
    const float* x    = (const float*)d_in[0];
    const float* wgt  = (const float*)d_in[1];
    const float* bias = (const float*)d_in[2];
    float* out = (float*)d_out;
    unsigned int* ws = (unsigned int*)d_ws;

    // pack weights into A-fragment layout (51200 B in d_ws)
    prep_weights_kernel<<<13, 256, 0, stream>>>(wgt, ws);

    dconv_kernel<<<3408, 256, 0, stream>>>(x, bias, (const bf16x8*)ws, out);
}

// Round 11
// 72.588 us; speedup vs baseline: 1.3419x; 1.0992x over previous
//
#include <hip/hip_runtime.h>
#include <hip/hip_bf16.h>

// DirectionalConv mode='down': out[b,co,d,h,w] =
//   sum_{ci,i,k} x[b,ci, d+i-2, h+i-2, w+k-2] * W[co,ci,i,0,k] + bias[co]
// x: (2,32,48,64,128) f32, W: (32,32,5,1,5), out: (2,32,48,68,128) f32.
//
// R11 = R8 structure (quad-diagonal blocks, col-per-lane staging, s=col&7
// swizzle, 1704-block XCD remap) with the MFMA core switched to
// mfma_f32_32x32x16_bf16: wave = 32co x 32w x 2 diag-outputs.

#define NB   2
#define CIN  32
#define COUT 32
#define DD   48
#define HH   64
#define WW   128
#define DOUT 48
#define HO   68
#define WO   128

#define RS   256            // ushorts per col = 32 16B-chunks (8 planes * 4 octs)
#define NCOL 132            // col = w + 2; cols 0,1,130,131 always zero

typedef __attribute__((ext_vector_type(8)))  short bf16x8;
typedef __attribute__((ext_vector_type(4)))  float f32x4;
typedef __attribute__((ext_vector_type(16))) float f32x16;

__device__ __forceinline__ unsigned short f32_to_bf16(float v) {
    unsigned int u; __builtin_memcpy(&u, &v, 4);
    u += 0x7FFFu + ((u >> 16) & 1u);        // RNE
    return (unsigned short)(u >> 16);
}
// packed pair conversion -> v_cvt_pk_bf16_f32 (1 instr for 2 floats)
__device__ __forceinline__ unsigned int pk2(float a, float b) {
    float2 t; t.x = a; t.y = b;
    __hip_bfloat162 r = __float22bfloat162_rn(t);
    unsigned int u; __builtin_memcpy(&u, &r, 4);
    return u;
}

// Pre-pack weights into 32x32x16 A-fragment order:
// frag f = kk*10 + c*2 + kh ; lane l: co = l&31, ci = kh*16 + (l>>5)*8 + jj.
__global__ void prep_weights_kernel(const float* __restrict__ wgt,
                                    unsigned int* __restrict__ ws) {
    int s = blockIdx.x * 256 + threadIdx.x;     // 50 frags * 64 lanes = 3200 slots
    if (s >= 3200) return;
    int f = s >> 6, l = s & 63;
    int kk = f / 10, rem = f - kk * 10;
    int c = rem >> 1, kh = rem & 1;
    int co  = l & 31;
    int cib = kh * 16 + (l >> 5) * 8;
    unsigned int u[4];
#pragma unroll
    for (int jp = 0; jp < 4; ++jp) {
        // weight flat index: co*800 + ci*25 + c*5 + kk
        float v0 = wgt[co * 800 + (cib + 2 * jp + 0) * 25 + c * 5 + kk];
        float v1 = wgt[co * 800 + (cib + 2 * jp + 1) * 25 + c * 5 + kk];
        u[jp] = (unsigned int)f32_to_bf16(v0) | ((unsigned int)f32_to_bf16(v1) << 16);
    }
    uint4 pack; pack.x = u[0]; pack.y = u[1]; pack.z = u[2]; pack.w = u[3];
    reinterpret_cast<uint4*>(ws)[s] = pack;
}

__global__ void __launch_bounds__(512, 4)
dconv_kernel(const float* __restrict__ x,
             const float* __restrict__ bias,
             const bf16x8* __restrict__ wsf,   // packed A fragments
             float* __restrict__ out) {
    __shared__ __align__(16) unsigned short xs[NCOL * RS];   // 67584 B

    const int tid  = threadIdx.x;
    const int lane = tid & 63;
    const int wv   = tid >> 6;          // 0..7
    const int ln31 = lane & 31;
    const int octl = lane >> 5;         // 0..1
    const int wt   = wv >> 1;           // w-tile 0..3 (32 wide)
    const int q0   = (wv & 1) * 2;      // diag-output pair base: 0 or 2

    // ---- quad-diagonal, XCD-chunked block remap (R8) ----
    int bid = blockIdx.x;
    int e   = (bid & 7) * 213 + (bid >> 3);
    int b   = (e >= 852) ? 1 : 0;
    int r0  = e - b * 852;
    int dlt = r0 / 12;
    int qq  = r0 - dlt * 12;
    const int d0 = 4 * qq;
    const int h0 = (d0 + dlt) % 71 - 3;     // -3..67

    // ---- zero the 4 always-zero halo cols (0,1,130,131), all 32 chunks ----
    if (tid < 128) {
        int colIdx = tid >> 5;              // 0..3
        int ch     = tid & 31;              // 0..31
        int col    = (colIdx < 2) ? colIdx : 128 + colIdx;
        f32x4 z = {};
        *reinterpret_cast<f32x4*>(&xs[col * RS + ch * 8]) = z;
    }

    // ---- stage 8 diagonal planes: col-per-lane, one b128 chunk per plane ----
    // wave role: oct = wv>>1 (ci octet), wh = wv&1 (w half); lane owns one col.
    {
        const int oct = wv >> 1, wh = wv & 1;
        const int w0  = wh * 64 + lane;     // 0..127
        const int col = w0 + 2;
        const int s   = col & 7;
        unsigned short* cbase = &xs[col * RS];
        const size_t plane = (size_t)DD * HH * WW;
        const float* xoct = x + ((size_t)b * CIN + oct * 8) * plane + w0;
#pragma unroll 4
        for (int j = 0; j < 8; ++j) {
            int dz = d0 + j - 2, hz = h0 + j - 2;
            float v[8];
#pragma unroll
            for (int k = 0; k < 8; ++k) v[k] = 0.f;
            if (((unsigned)dz < (unsigned)DD) && ((unsigned)hz < (unsigned)HH)) {
                const float* p = xoct + ((size_t)dz * HH + hz) * WW;
#pragma unroll
                for (int k = 0; k < 8; ++k) v[k] = p[(size_t)k * plane];
            }
            uint4 ch;
            ch.x = pk2(v[0], v[1]); ch.y = pk2(v[2], v[3]);
            ch.z = pk2(v[4], v[5]); ch.w = pk2(v[6], v[7]);
            int P = (j * 4 + oct) ^ s;
            *reinterpret_cast<uint4*>(cbase + P * 8) = ch;
        }
    }
    __syncthreads();

    // ---- MFMA 32x32x16: wave = (32co, 32w at wt, outputs q0..q0+1) ----
    // B-read for (plane j, k-half kh): col = wt*32 + ln31 + kk,
    // chunk = (j*4 + kh*2 + octl) ^ (col&7). Decompose:
    //   phys = (j ^ sb2)*4 + ((kh*2+octl) ^ s2), sb2=s>>2, s2=s&3;
    //   (q0+jo)^sb2 == q0 + (jo^sb2) (q0 even), so fold q0*32 into pointers
    //   and use jo*32 immediates with even/odd two-pointer trick.
    const bf16x8* wl = wsf + lane;          // frag f at wl[f*64]
    f32x16 acc[2] = {};                     // [qi]

#pragma unroll
    for (int kk = 0; kk < 5; ++kk) {
        bf16x8 a[10];                       // t = c*2 + kh
#pragma unroll
        for (int t = 0; t < 10; ++t) a[t] = wl[(kk * 10 + t) * 64];

        const int col = wt * 32 + ln31 + kk;        // <= 96+31+4 = 131
        const int s   = col & 7;
        const int sb2 = s >> 2;
        const int s2  = s & 3;
        const unsigned short* pc = &xs[col * RS + q0 * 32];
        const int o0 = (octl ^ s2) * 8;             // kh=0 chunk-low bits
        const int o1 = ((2 + octl) ^ s2) * 8;       // kh=1
        const unsigned short* pE0 = pc + o0 + sb2 * 32;
        const unsigned short* pO0 = pc + o0 - sb2 * 32;
        const unsigned short* pE1 = pc + o1 + sb2 * 32;
        const unsigned short* pO1 = pc + o1 - sb2 * 32;

        __builtin_amdgcn_s_setprio(1);
#pragma unroll
        for (int jo = 0; jo < 6; ++jo) {            // plane j = q0 + jo
#pragma unroll
            for (int kh = 0; kh < 2; ++kh) {
                const unsigned short* p =
                    (jo & 1) ? (kh ? pO1 : pO0) : (kh ? pE1 : pE0);
                bf16x8 bv = *reinterpret_cast<const bf16x8*>(p + jo * 32);
                const int qlo = (jo > 4) ? 1 : 0;
                const int qhi = (jo < 1) ? 0 : 1;
#pragma unroll
                for (int qi = qlo; qi <= qhi; ++qi) {
                    const int c = jo - qi;          // tap, compile-time 0..4
                    acc[qi] = __builtin_amdgcn_mfma_f32_32x32x16_bf16(
                        a[c * 2 + kh], bv, acc[qi], 0, 0, 0);
                }
            }
        }
        __builtin_amdgcn_s_setprio(0);
    }

    // ---- epilogue: C 32x32: col(w)=ln31, row(co)=(rg&3)+8*(rg>>2)+4*octl ----
    const int w = wt * 32 + ln31;
#pragma unroll
    for (int qi = 0; qi < 2; ++qi) {
        const int q  = q0 + qi;
        const int hq = h0 + q;
        if (hq < 0 || hq >= HO) continue;
        const int dq = d0 + q;
#pragma unroll
        for (int rg = 0; rg < 16; ++rg) {
            const int co = (rg & 3) + 8 * (rg >> 2) + 4 * octl;
            out[((((size_t)b * COUT + co) * DOUT + dq) * HO + hq) * WO + w] =
                acc[qi][rg] + bias[co];
        }
    }
}

extern "C" void kernel_launch(void* const* d_in, const int* in_sizes, int n_in,
                              void* d_out, int out_size, void* d_ws, size_t ws_size,
                              hipStream_t stream) {
    const float* x    = (const float*)d_in[0];
    const float* wgt  = (const float*)d_in[1];
    const float* bias = (const float*)d_in[2];
    float* out = (float*)d_out;
    unsigned int* ws = (unsigned int*)d_ws;

    // pack weights into 32x32x16 A-fragment layout (51200 B in d_ws)
    prep_weights_kernel<<<13, 256, 0, stream>>>(wgt, ws);

    dconv_kernel<<<1704, 512, 0, stream>>>(x, bias, (const bf16x8*)ws, out);
}

// Round 12
// 64.452 us; speedup vs baseline: 1.5113x; 1.1262x over previous
//
#include <hip/hip_runtime.h>
#include <hip/hip_bf16.h>

// DirectionalConv mode='down': out[b,co,d,h,w] =
//   sum_{ci,i,k} x[b,ci, d+i-2, h+i-2, w+k-2] * W[co,ci,i,0,k] + bias[co]
// x: (2,32,48,64,128) f32, W: (32,32,5,1,5), out: (2,32,48,68,128) f32.
//
// R12 = R8 staging/swizzle (col-per-lane, s = col&7, conflict-floor on both
// sides) + R5 wave shape: wave = 16-wide w-tile x BOTH co-halves x 4 q
// (acc[2][4], 10 A-frags per kk loaded in-loop, no cross-kk ping-pong).
// Halves LDS b128 reads vs R8 (no mt-duplicated B reads), read:MFMA = 1:6.

#define NB   2
#define CIN  32
#define COUT 32
#define DD   48
#define HH   64
#define WW   128
#define DOUT 48
#define HO   68
#define WO   128

#define RS   256            // ushorts per col = 32 16B-chunks (8 planes * 4 octs)
#define NCOL 132            // col = w + 2; cols 0,1,130,131 always zero

typedef __attribute__((ext_vector_type(8))) short bf16x8;
typedef __attribute__((ext_vector_type(4))) float f32x4;

__device__ __forceinline__ unsigned short f32_to_bf16(float v) {
    unsigned int u; __builtin_memcpy(&u, &v, 4);
    u += 0x7FFFu + ((u >> 16) & 1u);        // RNE
    return (unsigned short)(u >> 16);
}
// packed pair conversion -> v_cvt_pk_bf16_f32 (1 instr for 2 floats)
__device__ __forceinline__ unsigned int pk2(float a, float b) {
    float2 t; t.x = a; t.y = b;
    __hip_bfloat162 r = __float22bfloat162_rn(t);
    unsigned int u; __builtin_memcpy(&u, &r, 4);
    return u;
}

// Pre-pack weights into MFMA A-fragment order, kk-major (same as R8):
// frag f = (kk*5 + c)*2 + mt ; lane l ; 8 bf16 = W[mt*16+(l&15)][ci=(l>>4)*8+j][i=c][kk]
__global__ void prep_weights_kernel(const float* __restrict__ wgt,
                                    unsigned int* __restrict__ ws) {
    int s = blockIdx.x * 256 + threadIdx.x;     // 50 frags * 64 lanes = 3200 slots
    if (s >= 3200) return;
    int f = s >> 6, l = s & 63;
    int mt = f & 1, kkc = f >> 1;
    int kk = kkc / 5, c = kkc - kk * 5;         // kk-major
    int co = mt * 16 + (l & 15);
    int cib = (l >> 4) * 8;
    unsigned int u[4];
#pragma unroll
    for (int jp = 0; jp < 4; ++jp) {
        float v0 = wgt[co * 800 + (cib + 2 * jp + 0) * 25 + c * 5 + kk];
        float v1 = wgt[co * 800 + (cib + 2 * jp + 1) * 25 + c * 5 + kk];
        u[jp] = (unsigned int)f32_to_bf16(v0) | ((unsigned int)f32_to_bf16(v1) << 16);
    }
    uint4 pack; pack.x = u[0]; pack.y = u[1]; pack.z = u[2]; pack.w = u[3];
    reinterpret_cast<uint4*>(ws)[s] = pack;
}

__global__ void __launch_bounds__(512, 4)
dconv_kernel(const float* __restrict__ x,
             const float* __restrict__ bias,
             const bf16x8* __restrict__ wsf,   // packed A fragments
             float* __restrict__ out) {
    __shared__ __align__(16) unsigned short xs[NCOL * RS];   // 67584 B

    const int tid  = threadIdx.x;
    const int lane = tid & 63;
    const int wv   = tid >> 6;          // 0..7
    const int lr   = lane & 15;
    const int lg   = lane >> 4;
    const int wbase = wv * 16;          // 16-wide w-tile (MFMA phase)

    // ---- quad-diagonal, XCD-chunked block remap (R8) ----
    int bid = blockIdx.x;
    int e   = (bid & 7) * 213 + (bid >> 3);
    int b   = (e >= 852) ? 1 : 0;
    int r0  = e - b * 852;
    int dlt = r0 / 12;
    int qq  = r0 - dlt * 12;
    const int d0 = 4 * qq;
    const int h0 = (d0 + dlt) % 71 - 3;     // -3..67

    // ---- early: bias for both co-halves (hide under staging) ----
    const bf16x8* wl = wsf + lane;          // frag f at wl[f*64]
    float bs[8];
#pragma unroll
    for (int mt = 0; mt < 2; ++mt)
#pragma unroll
        for (int rg = 0; rg < 4; ++rg)
            bs[mt * 4 + rg] = bias[mt * 16 + lg * 4 + rg];

    // ---- zero the 4 always-zero halo cols (0,1,130,131), all 32 chunks ----
    if (tid < 128) {
        int colIdx = tid >> 5;              // 0..3
        int ch     = tid & 31;              // 0..31
        int col    = (colIdx < 2) ? colIdx : 128 + colIdx;
        f32x4 z = {};
        *reinterpret_cast<f32x4*>(&xs[col * RS + ch * 8]) = z;
    }

    // ---- stage 8 diagonal planes: col-per-lane, one b128 chunk per plane ----
    // wave role: oct = wv>>1 (ci octet), wh = wv&1 (w half); lane owns one col.
    {
        const int oct = wv >> 1, wh = wv & 1;
        const int w0  = wh * 64 + lane;     // 0..127
        const int col = w0 + 2;
        const int s   = col & 7;
        unsigned short* cbase = &xs[col * RS];
        const size_t plane = (size_t)DD * HH * WW;
        const float* xoct = x + ((size_t)b * CIN + oct * 8) * plane + w0;
#pragma unroll 4
        for (int j = 0; j < 8; ++j) {
            int dz = d0 + j - 2, hz = h0 + j - 2;
            float v[8];
#pragma unroll
            for (int k = 0; k < 8; ++k) v[k] = 0.f;
            if (((unsigned)dz < (unsigned)DD) && ((unsigned)hz < (unsigned)HH)) {
                const float* p = xoct + ((size_t)dz * HH + hz) * WW;
#pragma unroll
                for (int k = 0; k < 8; ++k) v[k] = p[(size_t)k * plane];
            }
            uint4 ch;
            ch.x = pk2(v[0], v[1]); ch.y = pk2(v[2], v[3]);
            ch.z = pk2(v[4], v[5]); ch.w = pk2(v[6], v[7]);
            int P = (j * 4 + oct) ^ s;
            *reinterpret_cast<uint4*>(cbase + P * 8) = ch;
        }
    }
    __syncthreads();

    // ---- MFMA: wave = (both mt, 16w at wbase, 4q); 8 independent acc chains ----
    f32x4 acc[2][4] = {};   // [mt][q]

#pragma unroll
    for (int kk = 0; kk < 5; ++kk) {
        bf16x8 a[10];                       // t = c*2 + mt, contiguous per kk
#pragma unroll
        for (int t = 0; t < 10; ++t) a[t] = wl[(kk * 10 + t) * 64];

        // phys chunk for (j, lg): P = (j ^ sb)*4 + (lg ^ (s&3)), sb = s>>2.
        // two-pointer form: even j -> pE + j*32, odd j -> pO + j*32 (ushorts).
        const int col = wbase + lr + kk;            // <= 112+15+4 = 131
        const int s   = col & 7;
        const int sb  = s >> 2;
        const int lg2 = lg ^ (s & 3);
        const unsigned short* pc = &xs[col * RS + lg2 * 8];
        const unsigned short* pE = pc + sb * 32;
        const unsigned short* pO = pc - sb * 32;

        __builtin_amdgcn_s_setprio(1);
#pragma unroll
        for (int j = 0; j < 8; ++j) {
            const unsigned short* p = (j & 1) ? pO : pE;
            bf16x8 bv = *reinterpret_cast<const bf16x8*>(p + j * 32);
            const int qlo = (j > 4) ? (j - 4) : 0;
            const int qhi = (j < 3) ? j : 3;
#pragma unroll
            for (int q = qlo; q <= qhi; ++q) {
                const int c = j - q;                // tap for output q at plane j
                acc[0][q] = __builtin_amdgcn_mfma_f32_16x16x32_bf16(
                    a[c * 2 + 0], bv, acc[0][q], 0, 0, 0);
                acc[1][q] = __builtin_amdgcn_mfma_f32_16x16x32_bf16(
                    a[c * 2 + 1], bv, acc[1][q], 0, 0, 0);
            }
        }
        __builtin_amdgcn_s_setprio(0);
    }

    // ---- epilogue: D col=lane&15 (w), row=(lane>>4)*4+reg (co) ----
    const int w = wbase + lr;
#pragma unroll
    for (int q = 0; q < 4; ++q) {
        const int hq = h0 + q;
        if (hq < 0 || hq >= HO) continue;
        const int dq = d0 + q;
#pragma unroll
        for (int mt = 0; mt < 2; ++mt) {
#pragma unroll
            for (int rg = 0; rg < 4; ++rg) {
                int co = mt * 16 + lg * 4 + rg;
                out[((((size_t)b * COUT + co) * DOUT + dq) * HO + hq) * WO + w] =
                    acc[mt][q][rg] + bs[mt * 4 + rg];
            }
        }
    }
}

extern "C" void kernel_launch(void* const* d_in, const int* in_sizes, int n_in,
                              void* d_out, int out_size, void* d_ws, size_t ws_size,
                              hipStream_t stream) {
    const float* x    = (const float*)d_in[0];
    const float* wgt  = (const float*)d_in[1];
    const float* bias = (const float*)d_in[2];
    float* out = (float*)d_out;
    unsigned int* ws = (unsigned int*)d_ws;

    // pack weights into A-fragment layout (51200 B in d_ws)
    prep_weights_kernel<<<13, 256, 0, stream>>>(wgt, ws);

    dconv_kernel<<<1704, 512, 0, stream>>>(x, bias, (const bf16x8*)ws, out);
}